// Round 3
// baseline (128.561 us; speedup 1.0000x reference)
//
#include <hip/hip_runtime.h>
#include <hip/hip_bf16.h>
#include <math.h>

#define M_ROWS 65536
#define NSPLINE 32
#define BM 64            // rows per block
#define WROWS 16         // rows per wave
#define GROUP 4          // splines per iteration
#define NITER (NSPLINE / GROUP)   // 8
#define YS 34            // fp32 words per task slot (34%32=2 -> 2-way alias, free; 8B-aligned)
#define WB_ELEMS (32 * 3 * 2 * 64 * 8)   // 98304 fp16

typedef __attribute__((ext_vector_type(8))) _Float16 half8;
typedef __attribute__((ext_vector_type(4))) float floatx4;

// ---------------------------------------------------------------------------
// R13 softplus: BRANCHLESS EXACT.  log(1+e^t) = max(t,0) + log(1+e^-|t|).
// 7 instrs, 2 transcendentals, ZERO branches.  R10/R12's poly+log1pf-fallback
// had a divergent branch per eval; with tail W-columns pushing |t|>1.1 at
// ~1e-3..1e-2 per eval, P(wave mixed) per site is tens of %, and each mixed
// wave serially runs the ~30-op log1pf tail -> explains the 2.3x gap between
// hand-counted VALU ops (~13us) and measured VALU busy (~29.5us), and the 34
// basic blocks that kept the compiler from hiding GEMM loads under spline
// VALU (why R11/R12's pipeline was a no-op).
// ---------------------------------------------------------------------------
__device__ __forceinline__ float softplus_fast(float t) {
    float e = __expf(-__builtin_fabsf(t));     // v_mul(-|t|*log2e) + v_exp
    return fmaxf(t, 0.0f) + __logf(1.0f + e);  // add + v_log + mul + max + add
}

// ---------------------------------------------------------------------------
// Pack W (48x1056 fp32) + bias (1056) into MFMA fragment layout, fp16.
// WH[sp][t][half][lane][j]:
//   k  = half*32 + (lane>>4)*8 + j   (k<48: W[k][col]; k==48: bias; else 0)
//   cl = t*16 + (lane&15), col = sp*33+cl  (cl>=33 -> zero pad)
// Used as the A operand (m = param = lane&15).  [unchanged from R10]
// ---------------------------------------------------------------------------
__global__ void pack_W(const float* __restrict__ W, const float* __restrict__ b,
                       _Float16* __restrict__ WH) {
    int idx = blockIdx.x * 256 + threadIdx.x;     // < 98304
    int j    = idx & 7;
    int lane = (idx >> 3) & 63;
    int half = (idx >> 9) & 1;
    int tmp  = idx >> 10;
    int t    = tmp % 3;
    int sp   = tmp / 3;
    int k  = half * 32 + ((lane >> 4) << 3) + j;
    int cl = t * 16 + (lane & 15);
    float v = 0.0f;
    if (cl < 33 && k <= 48) {
        int col = sp * 33 + cl;
        v = (k < 48) ? W[k * 1056 + col] : b[col];
    }
    WH[idx] = (_Float16)v;
}

// ---------------------------------------------------------------------------
// R13 = R12 pipeline (GEMM(g+1) before SPLINE(g)) + single-basic-block
// spline (branchless softplus, v_rcp divides).  The pipeline order only pays
// if the scheduler can actually interleave the GEMM chain with spline VALU;
// R12's 34 branch-fragmented blocks prevented that (R12 == R10 perf).
// Divides: 0.984/sew, 0.999/area, (in-loc)/w each compiled to ~10-op IEEE
// div sequences; v_rcp_f32 (~1e-5 rel err, vs 1.5e-2 tolerance) + mul.
// Correctness as R10/R12: wave-private LDS region; per-wave in-order DS.
// ---------------------------------------------------------------------------

#define GEMM_GROUP(GIDX)                                                      \
    {                                                                         \
      _Pragma("unroll")                                                       \
      for (int sp = 0; sp < GROUP; ++sp) {                                    \
        const int spg = (GIDX) * GROUP + sp;                                  \
        const int task = sp * 16 + cc;                                        \
        _Pragma("unroll")                                                     \
        for (int t = 0; t < 3; ++t) {                                         \
          const half8* p = (const half8*)WH + (size_t)(spg * 3 + t) * 128 + lane; \
          half8 b0 = p[0];                                                    \
          half8 b1 = p[64];                                                   \
          floatx4 acc = {0.f, 0.f, 0.f, 0.f};                                 \
          acc = __builtin_amdgcn_mfma_f32_16x16x32_f16(b0, a0, acc, 0, 0, 0); \
          acc = __builtin_amdgcn_mfma_f32_16x16x32_f16(b1, a1, acc, 0, 0, 0); \
          if (t < 2) {                                                        \
            float* dst = lds_wv + task * YS + t * 16 + q * 4;                 \
            *(float2*)dst       = make_float2(acc[0], acc[1]);                \
            *(float2*)(dst + 2) = make_float2(acc[2], acc[3]);                \
          } else if (q == 0) {                                                \
            lds_wv[task * YS + 32] = acc[0];  /* param 32 only */             \
          }                                                                   \
        }                                                                     \
      }                                                                       \
    }

#define READ_PV()                                                             \
    {                                                                         \
      const float* my = lds_wv + lane * YS;                                   \
      _Pragma("unroll")                                                       \
      for (int i = 0; i < 16; ++i) {                                          \
        float2 v = *(const float2*)(my + 2 * i);                              \
        pv[2 * i] = v.x; pv[2 * i + 1] = v.y;                                 \
      }                                                                       \
      pv[32] = my[32];                                                        \
    }

#define SPLINE(GIDX, INVAL)                                                   \
    {                                                                         \
      const int n = (GIDX) * GROUP + q;                                       \
      const float in = (INVAL);                                               \
      float wd[16];                                                           \
      float sew = 0.f;                                                        \
      _Pragma("unroll")                                                       \
      for (int i = 0; i < 16; ++i) {                                          \
        float e = __expf(pv[17 + i]);                                         \
        wd[i] = e; sew += e;                                                  \
      }                                                                       \
      const float inv_sew = 0.984f * __builtin_amdgcn_rcpf(sew);              \
      _Pragma("unroll")                                                       \
      for (int i = 0; i < 16; ++i) wd[i] = 0.001f + wd[i] * inv_sew;          \
      float h[17];                                                            \
      _Pragma("unroll")                                                       \
      for (int i = 0; i < 17; ++i)                                            \
        h[i] = softplus_fast(pv[i]) + 0.001f;                                 \
      float area = 0.f;                                                       \
      _Pragma("unroll")                                                       \
      for (int i = 0; i < 16; ++i) area += (h[i] + h[i + 1]) * 0.5f * wd[i];  \
      const float inv_area = 0.999f * __builtin_amdgcn_rcpf(area);            \
      _Pragma("unroll")                                                       \
      for (int i = 0; i < 17; ++i) h[i] = 0.001f + h[i] * inv_area;           \
      float loc = 0.f, cdfl = 0.f;                                            \
      float sel_loc = 0.f, sel_w = wd[0], sel_cdf = 0.f;                      \
      float sel_lh = h[0], sel_rh = h[1];                                     \
      _Pragma("unroll")                                                       \
      for (int bn = 1; bn < 16; ++bn) {                                       \
        cdfl = fmaf((h[bn - 1] + h[bn]) * 0.5f, wd[bn - 1], cdfl);            \
        loc += wd[bn - 1];                                                    \
        if (in >= loc) {                        /* monotone: last true wins */\
          sel_loc = loc; sel_w = wd[bn]; sel_cdf = cdfl;                      \
          sel_lh = h[bn]; sel_rh = h[bn + 1];                                 \
        }                                                                     \
      }                                                                       \
      const float alpha = (in - sel_loc) * __builtin_amdgcn_rcpf(sel_w);      \
      const float dh    = sel_rh - sel_lh;                                    \
      float o = ((0.5f * dh * sel_w) * alpha + sel_lh * sel_w) * alpha + sel_cdf; \
      o = fminf(fmaxf(o, 0.0f), 1.0f);                                        \
      out[(size_t)(row_base + cc) * 64 + 32 + n] = o;                         \
      ld_acc += __logf(fmaf(alpha, dh, sel_lh));                              \
    }

__global__ void __launch_bounds__(256, 4) fused_kernel(
    const float* __restrict__ z, const float* __restrict__ c,
    const _Float16* __restrict__ WH, float* __restrict__ out)
{
    __shared__ float lds_y[4 * 64 * YS];         // 34816 B

    const int tid  = threadIdx.x;
    const int w    = tid >> 6;
    const int lane = tid & 63;
    const int q    = lane >> 4;        // quad 0..3
    const int cc   = lane & 15;
    const int row_base = blockIdx.x * BM + w * WROWS;
    float* lds_wv = lds_y + w * (64 * YS);

    // ---- z2 passthrough: out[:, :32] = z[:, 32:64] for this wave's rows ----
    #pragma unroll
    for (int it = 0; it < 2; ++it) {
        int idx = it * 64 + lane;                 // 0..127 = 16 rows x 8 float4
        int rr  = row_base + (idx >> 3);
        int v4  = idx & 7;
        float4 val = *(const float4*)(z + (size_t)rr * 64 + 32 + v4 * 4);
        *(float4*)(out + (size_t)rr * 64 + v4 * 4) = val;
    }

    // ---- z2c fragments (fp16, persist): the B operand ---------------------
    // B[k=(q*8+j)][n=cc] = z2c[row cc][k]
    half8 a0, a1;
    {
        const float* zr = z + (size_t)(row_base + cc) * 64 + 32;
        float4 v0 = *(const float4*)(zr + q * 8);
        float4 v1 = *(const float4*)(zr + q * 8 + 4);
        a0[0]=(_Float16)v0.x; a0[1]=(_Float16)v0.y;
        a0[2]=(_Float16)v0.z; a0[3]=(_Float16)v0.w;
        a0[4]=(_Float16)v1.x; a0[5]=(_Float16)v1.y;
        a0[6]=(_Float16)v1.z; a0[7]=(_Float16)v1.w;
        if (q < 2) {
            const float* cr = c + (size_t)(row_base + cc) * 16 + q * 8;
            float4 u0 = *(const float4*)cr;
            float4 u1 = *(const float4*)(cr + 4);
            a1[0]=(_Float16)u0.x; a1[1]=(_Float16)u0.y;
            a1[2]=(_Float16)u0.z; a1[3]=(_Float16)u0.w;
            a1[4]=(_Float16)u1.x; a1[5]=(_Float16)u1.y;
            a1[6]=(_Float16)u1.z; a1[7]=(_Float16)u1.w;
        } else {
            #pragma unroll
            for (int j = 0; j < 8; ++j) a1[j] = (_Float16)0.0f;
            if (q == 2) a1[0] = (_Float16)1.0f;   // k=48 bias row
        }
    }

    // z1 base for this lane's spline inputs: z[row cc][n = g*4 + q]
    const float* z1p = z + (size_t)(row_base + cc) * 64 + q;

    float pv[33];

    // ---- prologue: GEMM group 0 -> LDS -> pv registers (one exposed chain)
    GEMM_GROUP(0);
    READ_PV();

    float ld_acc = 0.0f;

    // ---- pipelined main loop: GEMM(g+1) overlaps spline(g) ----------------
    #pragma unroll 1
    for (int g = 0; g < NITER - 1; ++g) {
        const float in_g = z1p[g * 4];   // hot L1/L2 line; issues early
        GEMM_GROUP(g + 1);               // loads+MFMA+ds_write, independent of pv
        SPLINE(g, in_g);                 // single-BB VALU from registers
        READ_PV();                       // after writes (in-order DS); latency
                                         // hides under next iter's GEMM issue
    }
    {
        const float in_l = z1p[(NITER - 1) * 4];
        SPLINE(NITER - 1, in_l);
    }

    // ---- logdet: lanes {cc, cc+16, cc+32, cc+48} hold row cc's partials ---
    ld_acc += __shfl_down(ld_acc, 32, 64);
    ld_acc += __shfl_down(ld_acc, 16, 64);
    if (q == 0)
        out[(size_t)M_ROWS * 64 + row_base + cc] = ld_acc;
}

extern "C" void kernel_launch(void* const* d_in, const int* in_sizes, int n_in,
                              void* d_out, int out_size, void* d_ws, size_t ws_size,
                              hipStream_t stream) {
    const float* c = (const float*)d_in[0];   // (M, 16)
    const float* z = (const float*)d_in[1];   // (M, 64)
    const float* W = (const float*)d_in[2];   // (48, 1056)
    const float* b = (const float*)d_in[3];   // (1056,)
    float* out = (float*)d_out;               // M*64 (x) then M (logdet)
    _Float16* WH = (_Float16*)d_ws;           // 98304 fp16 = 192 KiB

    pack_W<<<WB_ELEMS / 256, 256, 0, stream>>>(W, b, WH);
    fused_kernel<<<M_ROWS / BM, 256, 0, stream>>>(z, c, WH, out);
}

// Round 4
// 111.537 us; speedup vs baseline: 1.1526x; 1.1526x over previous
//
#include <hip/hip_runtime.h>
#include <hip/hip_bf16.h>
#include <math.h>

#define M_ROWS 65536
#define NSPLINE 32
#define BM 64            // rows per block
#define WROWS 16         // rows per wave
#define GROUP 4          // splines per iteration (one per quad q)
#define NITER (NSPLINE / GROUP)   // 8
#define NTILE 9          // ceil(33 params / 4-per-lane) MFMA tiles per group
#define WB_ELEMS (NITER * NTILE * 2 * 64 * 8)   // 73728 fp16 = 144 KiB

typedef __attribute__((ext_vector_type(8))) _Float16 half8;
typedef __attribute__((ext_vector_type(4))) float floatx4;

// R14: back to the R8/R10-proven poly softplus (full-rate FMA path; the
// branch's fallback is rare enough that the wave almost never diverges).
// R13's "branchless exact" used 2 quarter-rate transcendentals per eval and
// regressed 9.5us -- trans-pipe cost, not divergence, was the difference.
__device__ __forceinline__ float softplus_fast(float t) {
    float u = t * t;
    if (u > 1.21f) return log1pf(__expf(t));   // rare, exact
    float p = fmaf(u, -2.6352e-5f, 3.4722222e-4f);
    p = fmaf(u, p, -5.2083333e-3f);
    p = fmaf(u, p, 0.125f);
    p = fmaf(u, p, 0.69314718f);
    return fmaf(t, 0.5f, p);
}

// ---------------------------------------------------------------------------
// R14 pack: the transpose lives HERE now, not in LDS.
// The old layout put m = param-within-spline, forcing an LDS round-trip so
// each spline lane could gather its 33 params (34KB LDS -> 4 blocks/CU, 2.1M
// conflict cycles, ~37 DS ops/group). But W's columns are independent: we are
// free to permute what each m-slot computes. New m-mapping per tile tau:
//   m = (spline-sub q_m)*4 + r  ->  column (spline = g*4+q_m, param = tau*4+r)
// MFMA D-layout (m = (lane>>4)*4+reg, n = lane&15) then lands param tau*4+r
// of spline g*4+q DIRECTLY in lane (q,cc)'s accumulator: zero LDS, zero
// shuffles. 9 tiles cover 33 params (3 wasted m-slots vs 15 before):
// MFMAs and WH loads per group drop 24 -> 18.
// A-fragment element layout (proven by the working R10 pack):
//   lane L, elem j: m = L&15, k = half*32 + (L>>4)*8 + j
//   k<48: W[k][col]; k==48: bias (paired with B=1.0); else 0.
// ---------------------------------------------------------------------------
__global__ void pack_W(const float* __restrict__ W, const float* __restrict__ b,
                       _Float16* __restrict__ WH) {
    int idx = blockIdx.x * 256 + threadIdx.x;     // < 73728
    int j    = idx & 7;
    int lane = (idx >> 3) & 63;
    int half = (idx >> 9) & 1;
    int tile = idx >> 10;        // 0..71 = g*NTILE + tau
    int tau  = tile % NTILE;
    int g    = tile / NTILE;
    int m  = lane & 15;
    int k  = half * 32 + ((lane >> 4) << 3) + j;
    int spline = g * 4 + (m >> 2);
    int param  = tau * 4 + (m & 3);
    float v = 0.0f;
    if (param < 33 && k <= 48) {
        int col = spline * 33 + param;
        v = (k < 48) ? W[k * 1056 + col] : b[col];
    }
    WH[idx] = (_Float16)v;
}

// pv[p] lives in the MFMA accumulators themselves; all spline loops are
// fully unrolled so every index is compile-time (no scratch; rule #20).
#define PV(p) (acc[(p) >> 2][(p) & 3])

// ---------------------------------------------------------------------------
// R14 fused: NO __shared__ at all. Occupancy cap moves from LDS (4 blocks/CU)
// to VGPR; __launch_bounds__(256,5) asks for 5 blocks/CU (VGPR cap ~102; live
// estimate ~85). Per group g: 18 b128 WH loads + 18 MFMA accumulate the 33
// spline params straight into this lane's registers, then the spline runs on
// them. No DS ops -> no conflicts, no LDS latency in the chain; WH L2 traffic
// -25%. Spline numerics = R10 poly softplus + R13-proven rcp divides.
// ---------------------------------------------------------------------------
__global__ void __launch_bounds__(256, 5) fused_kernel(
    const float* __restrict__ z, const float* __restrict__ c,
    const _Float16* __restrict__ WH, float* __restrict__ out)
{
    const int tid  = threadIdx.x;
    const int w    = tid >> 6;
    const int lane = tid & 63;
    const int q    = lane >> 4;        // quad 0..3 = spline-sub within group
    const int cc   = lane & 15;        // row within wave
    const int row_base = blockIdx.x * BM + w * WROWS;

    // ---- z2 passthrough: out[:, :32] = z[:, 32:64] for this wave's rows ----
    #pragma unroll
    for (int it = 0; it < 2; ++it) {
        int idx = it * 64 + lane;                 // 0..127 = 16 rows x 8 float4
        int rr  = row_base + (idx >> 3);
        int v4  = idx & 7;
        float4 val = *(const float4*)(z + (size_t)rr * 64 + 32 + v4 * 4);
        *(float4*)(out + (size_t)rr * 64 + v4 * 4) = val;
    }

    // ---- z2c fragments (fp16, persist): the B operand ---------------------
    // B[k=(q*8+j)][n=cc] = z2c[row cc][k]
    half8 a0, a1;
    {
        const float* zr = z + (size_t)(row_base + cc) * 64 + 32;
        float4 v0 = *(const float4*)(zr + q * 8);
        float4 v1 = *(const float4*)(zr + q * 8 + 4);
        a0[0]=(_Float16)v0.x; a0[1]=(_Float16)v0.y;
        a0[2]=(_Float16)v0.z; a0[3]=(_Float16)v0.w;
        a0[4]=(_Float16)v1.x; a0[5]=(_Float16)v1.y;
        a0[6]=(_Float16)v1.z; a0[7]=(_Float16)v1.w;
        if (q < 2) {
            const float* cr = c + (size_t)(row_base + cc) * 16 + q * 8;
            float4 u0 = *(const float4*)cr;
            float4 u1 = *(const float4*)(cr + 4);
            a1[0]=(_Float16)u0.x; a1[1]=(_Float16)u0.y;
            a1[2]=(_Float16)u0.z; a1[3]=(_Float16)u0.w;
            a1[4]=(_Float16)u1.x; a1[5]=(_Float16)u1.y;
            a1[6]=(_Float16)u1.z; a1[7]=(_Float16)u1.w;
        } else {
            #pragma unroll
            for (int j = 0; j < 8; ++j) a1[j] = (_Float16)0.0f;
            if (q == 2) a1[0] = (_Float16)1.0f;   // k=48 bias row
        }
    }

    // z1 base for this lane's spline inputs: z[row cc][n = g*4 + q]
    const float* z1p = z + (size_t)(row_base + cc) * 64 + q;

    float ld_acc = 0.0f;

    #pragma unroll 1
    for (int g = 0; g < NITER; ++g) {
        const float in = z1p[g * 4];   // hot L1 line (read for a0 already)

        // ---- GEMM: 9 tiles x (K=32 + K=16+bias) -> pv in registers --------
        floatx4 acc[NTILE];
        const half8* base = (const half8*)WH + (size_t)g * (NTILE * 2 * 64) + lane;
        #pragma unroll
        for (int t = 0; t < NTILE; ++t) {
            half8 w0 = base[(t * 2 + 0) * 64];
            half8 w1 = base[(t * 2 + 1) * 64];
            floatx4 a = {0.f, 0.f, 0.f, 0.f};
            a = __builtin_amdgcn_mfma_f32_16x16x32_f16(w0, a0, a, 0, 0, 0);
            a = __builtin_amdgcn_mfma_f32_16x16x32_f16(w1, a1, a, 0, 0, 0);
            acc[t] = a;
        }
        // lane (q,cc) now holds PV(p) = y[row cc][spline g*4+q][param p],
        // p = 0..32 (slots 33..35 are zero-padded columns, unused).

        // ---- spline on registers -----------------------------------------
        const int n = g * GROUP + q;

        float wd[16];
        float sew = 0.f;
        #pragma unroll
        for (int i = 0; i < 16; ++i) {
            float e = __expf(PV(17 + i));
            wd[i] = e; sew += e;
        }
        const float inv_sew = 0.984f * __builtin_amdgcn_rcpf(sew);
        #pragma unroll
        for (int i = 0; i < 16; ++i) wd[i] = 0.001f + wd[i] * inv_sew;

        float h[17];
        #pragma unroll
        for (int i = 0; i < 17; ++i)
            h[i] = softplus_fast(PV(i)) + 0.001f;

        float area = 0.f;
        #pragma unroll
        for (int i = 0; i < 16; ++i) area += (h[i] + h[i + 1]) * 0.5f * wd[i];
        const float inv_area = 0.999f * __builtin_amdgcn_rcpf(area);
        #pragma unroll
        for (int i = 0; i < 17; ++i) h[i] = 0.001f + h[i] * inv_area;

        float loc = 0.f, cdfl = 0.f;
        float sel_loc = 0.f, sel_w = wd[0], sel_cdf = 0.f;
        float sel_lh = h[0], sel_rh = h[1];
        #pragma unroll
        for (int bn = 1; bn < 16; ++bn) {
            cdfl = fmaf((h[bn - 1] + h[bn]) * 0.5f, wd[bn - 1], cdfl);
            loc += wd[bn - 1];
            if (in >= loc) {                        // monotone: last true wins
                sel_loc = loc; sel_w = wd[bn]; sel_cdf = cdfl;
                sel_lh = h[bn]; sel_rh = h[bn + 1];
            }
        }

        const float alpha = (in - sel_loc) * __builtin_amdgcn_rcpf(sel_w);
        const float dh    = sel_rh - sel_lh;
        float o = ((0.5f * dh * sel_w) * alpha + sel_lh * sel_w) * alpha + sel_cdf;
        o = fminf(fmaxf(o, 0.0f), 1.0f);
        out[(size_t)(row_base + cc) * 64 + 32 + n] = o;
        ld_acc += __logf(fmaf(alpha, dh, sel_lh));
    }

    // ---- logdet: lanes {cc, cc+16, cc+32, cc+48} hold row cc's partials ---
    ld_acc += __shfl_down(ld_acc, 32, 64);
    ld_acc += __shfl_down(ld_acc, 16, 64);
    if (q == 0)
        out[(size_t)M_ROWS * 64 + row_base + cc] = ld_acc;
}

extern "C" void kernel_launch(void* const* d_in, const int* in_sizes, int n_in,
                              void* d_out, int out_size, void* d_ws, size_t ws_size,
                              hipStream_t stream) {
    const float* c = (const float*)d_in[0];   // (M, 16)
    const float* z = (const float*)d_in[1];   // (M, 64)
    const float* W = (const float*)d_in[2];   // (48, 1056)
    const float* b = (const float*)d_in[3];   // (1056,)
    float* out = (float*)d_out;               // M*64 (x) then M (logdet)
    _Float16* WH = (_Float16*)d_ws;           // 73728 fp16 = 144 KiB

    pack_W<<<WB_ELEMS / 256, 256, 0, stream>>>(W, b, WH);
    fused_kernel<<<M_ROWS / BM, 256, 0, stream>>>(z, c, WH, out);
}